// Round 18
// baseline (366.211 us; speedup 1.0000x reference)
//
#include <hip/hip_runtime.h>
#include <hip/hip_bf16.h>
#include <stdint.h>

#define VOCAB 30000
#define EMBED 256
#define HID   128
#define BB    256
#define TT    512
#define G4    512        // gate columns per direction
#define GWH   1024       // f16 columns in EW2 ([dir][u][g] packed)
#define BPB   4          // batches per lstm block (D-rows 0,4,8,12)
#define HSTR  160        // f16 stride per batch row in h_lds (320 B)

typedef _Float16 f16x8 __attribute__((ext_vector_type(8)));
typedef _Float16 f16x4 __attribute__((ext_vector_type(4)));
typedef float    f32x4 __attribute__((ext_vector_type(4)));

// gate scales folded into EW / Wp / U at build time:
//   i,f,o : z' = -log2(e)  * z   -> sigm = rcp(1 + exp2(z'))
//   g     : z' = +2log2(e) * z   -> tanh = 1 - 2*rcp(1 + exp2(z'))
#define S_IFO (-1.4426950408889634f)
#define S_G   ( 2.8853900817779268f)

__device__ __forceinline__ float fexp2(float x){
#if __has_builtin(__builtin_amdgcn_exp2f)
  return __builtin_amdgcn_exp2f(x);
#else
  return exp2f(x);
#endif
}
__device__ __forceinline__ float frcp(float x){
#if __has_builtin(__builtin_amdgcn_rcpf)
  return __builtin_amdgcn_rcpf(x);
#else
  return 1.0f/x;
#endif
}
__device__ __forceinline__ float sigm_p(float zp){ return frcp(1.0f + fexp2(zp)); }
__device__ __forceinline__ float tanh_p(float zp){ return 1.0f - 2.0f*frcp(1.0f + fexp2(zp)); }
__device__ __forceinline__ float tanh_rt(float x){ return 1.0f - 2.0f*frcp(1.0f + fexp2(S_G*x)); }

// ---------------------------------------------------------------------------
// Kernel 0: pack W into B-fragment layout, f16, pre-scaled.
// Wp[dirc][kt][c][hi][j] ; c = u*4+g (packed col), k = kt*32 + hi*8 + j.
// ---------------------------------------------------------------------------
__global__ __launch_bounds__(256) void wpack(
    const float* __restrict__ Wf, const float* __restrict__ Wb,
    _Float16* __restrict__ Wp)
{
  const int idx  = blockIdx.x*256 + threadIdx.x;   // 32768 = 2*8*512*4
  const int hi   = idx & 3;
  const int c    = (idx >> 2) & 511;
  const int kt   = (idx >> 11) & 7;
  const int dirc = idx >> 14;
  const float* W = dirc ? Wb : Wf;
  const int g = c & 3, u = c >> 2;
  const int cg = g*128 + u;                        // original column
  const float gs = (g == 2) ? S_G : S_IFO;
  f16x8 v;
  #pragma unroll
  for (int j = 0; j < 8; ++j)
    v[j] = (_Float16)(W[(size_t)(kt*32 + hi*8 + j)*G4 + cg] * gs);
  *(f16x8*)&Wp[(size_t)idx*8] = v;
}

// ---------------------------------------------------------------------------
// Kernel 1: EW2[v][dirc*512 + c] = f16( emb[v]@W(c)*gsc + b*gsc )
// Grid (469, 4): y = dirc*2 + u-half. A-tile staged once per block, u-loop
// over 4 groups (B = single f16x8 loads from Wp). Balances A-restage L3
// traffic (123 MB, was 491 at y=16) against block-level parallelism
// (1876 blocks, was 938 at y=2 which regressed).
// ---------------------------------------------------------------------------
__global__ __launch_bounds__(256, 4) void embw_mfma(
    const float* __restrict__ emb,
    const _Float16* __restrict__ Wp,
    const float* __restrict__ bf, const float* __restrict__ bb,
    _Float16* __restrict__ EW)
{
  __shared__ _Float16 As[64*EMBED];   // 32 KB
  const int tid  = threadIdx.x;
  const int l    = tid & 63;
  const int w    = tid >> 6;
  const int r0   = blockIdx.x * 64;
  const int dirc = blockIdx.y >> 1;
  const int u00  = (blockIdx.y & 1) * 64;   // u-half base
  const int nr   = min(64, VOCAB - r0);

  const float4* asrc = (const float4*)(emb + (size_t)r0*EMBED);
  for (int i = tid; i < nr*(EMBED/4); i += 256){
    float4 v = asrc[i];
    const int row = i >> 6;
    const int kc  = (i & 63) * 4;
    const int ks  = kc ^ ((row & 7) << 3);
    _Float16* dst = &As[row*EMBED + ks];
    dst[0]=(_Float16)v.x; dst[1]=(_Float16)v.y;
    dst[2]=(_Float16)v.z; dst[3]=(_Float16)v.w;
  }
  __syncthreads();

  const int cl = w*16 + (l & 15);
  const int hi = l >> 4;
  const int g  = cl & 3;
  const float gsc = (g == 2) ? S_G : S_IFO;
  const float* bbase = dirc ? bb : bf;

  for (int u0g = 0; u0g < 4; ++u0g){
    const int u0 = u00 + u0g*16;
    const int c  = u0*4 + cl;           // packed col in [0,512)
    const int ul = cl >> 2;
    const int cg = g*128 + u0 + ul;     // original column

    f32x4 acc[4] = {{0,0,0,0},{0,0,0,0},{0,0,0,0},{0,0,0,0}};

    #pragma unroll
    for (int kt = 0; kt < 8; ++kt){
      const f16x8 bfrag = *(const f16x8*)&Wp[((size_t)((dirc*8 + kt)*512 + c)*4 + hi)*8];
      const int kb = kt*32 + hi*8;
      #pragma unroll
      for (int m = 0; m < 4; ++m){
        const int row = m*16 + (l & 15);
        const int ks  = kb ^ ((row & 7) << 3);
        f16x8 afrag = *(const f16x8*)&As[row*EMBED + ks];
        acc[m] = __builtin_amdgcn_mfma_f32_16x16x32_f16(afrag, bfrag, acc[m], 0, 0, 0);
      }
    }

    const float bsc = bbase[cg] * gsc;
    const int   co  = dirc*512 + c;     // f16 col in EW2
    #pragma unroll
    for (int m = 0; m < 4; ++m){
      #pragma unroll
      for (int r = 0; r < 4; ++r){
        const int vrow = r0 + m*16 + (l >> 4)*4 + r;
        if (vrow < VOCAB)
          EW[(size_t)vrow*GWH + co] = (_Float16)(acc[m][r] + bsc);
      }
    }
  }
}

// ---------------------------------------------------------------------------
// Kernel 2: recurrence, BPB=4 (grid 128, ~1 block/CU) — r15 verbatim
// (triple-confirmed 250 us; design-space audit shows no config below
// ~1100 cyc/step: MFMA issue 620 cyc/CU/step is invariant for <=256-block
// decompositions, VALU ~500 cannot overlap within a barrier-locked block).
// ---------------------------------------------------------------------------
__global__ __launch_bounds__(512, 2) void lstm_b4(
    const int*      __restrict__ tokens,
    const _Float16* __restrict__ EW,
    const float*    __restrict__ Ufw, const float* __restrict__ Ubw,
    float* __restrict__ out)
{
  __shared__ _Float16 h_lds[2][BPB*HSTR];  // 2 x 1.25 KB
  __shared__ int      tok_lds[BPB*TT];     // 8 KB

  const int tid = threadIdx.x;
  const int l   = tid & 63;
  const int w   = tid >> 6;               // wave 0..7
  const int lr  = l & 15;
  const int hi  = l >> 4;
  const int dir = blockIdx.x & 1;
  const int b0  = (blockIdx.x >> 1) * BPB;

  for (int i = tid; i < 2*BPB*HSTR; i += 512) ((_Float16*)h_lds)[i] = (_Float16)0.f;
  for (int i = tid; i < BPB*TT; i += 512)
    tok_lds[i] = tokens[(b0 + (i >> 9))*TT + (i & 511)];
  __syncthreads();

  // ---- resident U B-fragments (pre-scaled): ub[kt][gate], 64 VGPRs ----
  const float* U = dir ? Ubw : Ufw;
  f16x8 ub[4][4];
  #pragma unroll
  for (int kt = 0; kt < 4; ++kt){
    #pragma unroll
    for (int g = 0; g < 4; ++g){
      const int   col = g*128 + w*16 + lr;
      const float gs  = (g == 2) ? S_G : S_IFO;
      f16x8 f;
      #pragma unroll
      for (int j = 0; j < 8; ++j)
        f[j] = (_Float16)(U[(size_t)(kt*32 + hi*8 + j)*G4 + col] * gs);
      ub[kt][g] = f;
    }
  }

  const int bsel = lr >> 2;            // A-row 4j -> batch j (others dup)
  const int q    = hi;                 // gate batch for this lane
  const int u    = w*16 + lr;          // gate hidden unit

  float creg = 0.f, hfin = 0.f;
  const _Float16* ebase = EW + dir*512 + u*4;

  // persistent accumulators: regs 1-3 accumulate garbage, never read
  f32x4 aP[4];
  #pragma unroll
  for (int g = 0; g < 4; ++g) aP[g] = (f32x4){0.f,0.f,0.f,0.f};

  #define AADDR(S) ({ int ss_ = (S); ss_ = ss_ < TT ? ss_ : TT-1;            \
                      const int tt_ = dir ? (TT-1-ss_) : ss_;                \
                      ebase + (size_t)tok_lds[q*TT + tt_]*GWH; })

  f16x4 xwA = *(const f16x4*)AADDR(0);
  f16x4 xwB = *(const f16x4*)AADDR(1);
  const _Float16* adA = AADDR(2);
  const _Float16* adB = AADDR(3);

  #define STEP(XW, AD, SCUR, CUR)                                            \
  {                                                                          \
    const int t_ = dir ? (TT-1-(SCUR)) : (SCUR);                             \
    f16x8 ha[4];                                                             \
    _Pragma("unroll")                                                        \
    for (int kt = 0; kt < 4; ++kt)                                           \
      ha[kt] = *(const f16x8*)&h_lds[CUR][bsel*HSTR + kt*32 + hi*8];         \
    _Pragma("unroll")                                                        \
    for (int g = 0; g < 4; ++g) aP[g][0] = (float)XW[g];                     \
    XW = *(const f16x4*)AD;            /* reload this slot for SCUR+2 */     \
    AD = AADDR((SCUR)+4);              /* address for the next reload */     \
    _Pragma("unroll")                                                        \
    for (int kt = 0; kt < 4; ++kt){                                          \
      _Pragma("unroll")                                                      \
      for (int g = 0; g < 4; ++g)                                            \
        aP[g] = __builtin_amdgcn_mfma_f32_16x16x32_f16(ha[kt], ub[kt][g], aP[g], 0,0,0); \
    }                                                                        \
    {                                                                        \
      const float si = sigm_p(aP[0][0]);                                     \
      const float sf = sigm_p(aP[1][0]);                                     \
      const float tg = tanh_p(aP[2][0]);                                     \
      const float so = sigm_p(aP[3][0]);                                     \
      const float cn = sf*creg + si*tg;                                      \
      creg = cn;                                                             \
      const float hh = so*tanh_rt(cn);                                       \
      hfin = hh;                                                             \
      h_lds[(CUR)^1][q*HSTR + u] = (_Float16)hh;                             \
      out[((size_t)(b0+q)*TT + t_)*(2*HID) + (size_t)dir*HID + u] = hh;      \
    }                                                                        \
    asm volatile("s_waitcnt lgkmcnt(0)" ::: "memory");                       \
    __builtin_amdgcn_s_barrier();                                            \
  }

  for (int s = 0; s < TT; s += 2){
    STEP(xwA, adA, s,     0)
    STEP(xwB, adB, s + 1, 1)
  }
  #undef STEP
  #undef AADDR

  // ---- final h_T / c_T (each thread owns one (batch,unit)) ----
  {
    const size_t O1  = (size_t)BB*TT*(2*HID);
    const size_t idx = (size_t)(b0+q)*HID + u;
    if (dir == 0){
      out[O1                    + idx] = hfin;
      out[O1 +   (size_t)BB*HID + idx] = creg;
    } else {
      out[O1 + 2*(size_t)BB*HID + idx] = hfin;
      out[O1 + 3*(size_t)BB*HID + idx] = creg;
    }
  }
}

extern "C" void kernel_launch(void* const* d_in, const int* in_sizes, int n_in,
                              void* d_out, int out_size, void* d_ws, size_t ws_size,
                              hipStream_t stream)
{
  const int*   tokens = (const int*)  d_in[0];
  const float* emb    = (const float*)d_in[1];
  const float* Wf     = (const float*)d_in[2];
  const float* Ufw    = (const float*)d_in[3];
  const float* bf     = (const float*)d_in[4];
  const float* Wb     = (const float*)d_in[5];
  const float* Ubw    = (const float*)d_in[6];
  const float* bb     = (const float*)d_in[7];
  float* out = (float*)d_out;
  _Float16* EW = (_Float16*)d_ws;                       // 61.44 MB
  _Float16* Wp = (_Float16*)d_ws + (size_t)VOCAB*GWH;   // +1 MB packed W

  wpack<<<128, 256, 0, stream>>>(Wf, Wb, Wp);
  embw_mfma<<<dim3((VOCAB + 63)/64, 4), 256, 0, stream>>>(emb, Wp, bf, bb, EW);
  lstm_b4<<<(BB/BPB)*2, 512, 0, stream>>>(tokens, EW, Ufw, Ubw, out);
}

// Round 19
// 321.661 us; speedup vs baseline: 1.1385x; 1.1385x over previous
//
#include <hip/hip_runtime.h>
#include <hip/hip_bf16.h>
#include <stdint.h>

#define VOCAB 30000
#define EMBED 256
#define HID   128
#define BB    256
#define TT    512
#define G4    512        // gate columns per direction
#define GWH   1024       // f16 columns in EW2 ([dir][u][g] packed)
#define BPB   4          // batches per lstm block (D-rows 0,4,8,12)
#define HSTR  160        // f16 stride per batch row in h_lds (320 B)

typedef _Float16 f16x8 __attribute__((ext_vector_type(8)));
typedef _Float16 f16x4 __attribute__((ext_vector_type(4)));
typedef float    f32x4 __attribute__((ext_vector_type(4)));

// gate scales folded into EW / Wp / U at build time:
//   i,f,o : z' = -log2(e)  * z   -> sigm = rcp(1 + exp2(z'))
//   g     : z' = +2log2(e) * z   -> tanh = 1 - 2*rcp(1 + exp2(z'))
#define S_IFO (-1.4426950408889634f)
#define S_G   ( 2.8853900817779268f)

__device__ __forceinline__ float fexp2(float x){
#if __has_builtin(__builtin_amdgcn_exp2f)
  return __builtin_amdgcn_exp2f(x);
#else
  return exp2f(x);
#endif
}
__device__ __forceinline__ float frcp(float x){
#if __has_builtin(__builtin_amdgcn_rcpf)
  return __builtin_amdgcn_rcpf(x);
#else
  return 1.0f/x;
#endif
}
__device__ __forceinline__ float sigm_p(float zp){ return frcp(1.0f + fexp2(zp)); }
__device__ __forceinline__ float tanh_p(float zp){ return 1.0f - 2.0f*frcp(1.0f + fexp2(zp)); }
__device__ __forceinline__ float tanh_rt(float x){ return 1.0f - 2.0f*frcp(1.0f + fexp2(S_G*x)); }

// ---------------------------------------------------------------------------
// Kernel 0: pack W into B-fragment layout, f16, pre-scaled.
// Wp[dirc][kt][c][hi][j] ; c = u*4+g (packed col), k = kt*32 + hi*8 + j.
// ---------------------------------------------------------------------------
__global__ __launch_bounds__(256) void wpack(
    const float* __restrict__ Wf, const float* __restrict__ Wb,
    _Float16* __restrict__ Wp)
{
  const int idx  = blockIdx.x*256 + threadIdx.x;   // 32768 = 2*8*512*4
  const int hi   = idx & 3;
  const int c    = (idx >> 2) & 511;
  const int kt   = (idx >> 11) & 7;
  const int dirc = idx >> 14;
  const float* W = dirc ? Wb : Wf;
  const int g = c & 3, u = c >> 2;
  const int cg = g*128 + u;                        // original column
  const float gs = (g == 2) ? S_G : S_IFO;
  f16x8 v;
  #pragma unroll
  for (int j = 0; j < 8; ++j)
    v[j] = (_Float16)(W[(size_t)(kt*32 + hi*8 + j)*G4 + cg] * gs);
  *(f16x8*)&Wp[(size_t)idx*8] = v;
}

// ---------------------------------------------------------------------------
// Kernel 1: EW2[v][dirc*512 + c] = f16( emb[v]@W(c)*gsc + b*gsc )
// Grid (469, 16) — measured optimum of the y-sweep {2,4,16}: full block
// parallelism beats traffic reduction (A-restage flows through L3 at its
// effective BW). B-fragments are single f16x8 loads from packed Wp.
// ---------------------------------------------------------------------------
__global__ __launch_bounds__(256, 4) void embw_mfma(
    const float* __restrict__ emb,
    const _Float16* __restrict__ Wp,
    const float* __restrict__ bf, const float* __restrict__ bb,
    _Float16* __restrict__ EW)
{
  __shared__ _Float16 As[64*EMBED];   // 32 KB
  const int tid  = threadIdx.x;
  const int l    = tid & 63;
  const int w    = tid >> 6;
  const int r0   = blockIdx.x * 64;
  const int dirc = blockIdx.y >> 3;
  const int u0   = (blockIdx.y & 7) * 16;
  const int nr   = min(64, VOCAB - r0);

  const float4* asrc = (const float4*)(emb + (size_t)r0*EMBED);
  for (int i = tid; i < nr*(EMBED/4); i += 256){
    float4 v = asrc[i];
    const int row = i >> 6;
    const int kc  = (i & 63) * 4;
    const int ks  = kc ^ ((row & 7) << 3);
    _Float16* dst = &As[row*EMBED + ks];
    dst[0]=(_Float16)v.x; dst[1]=(_Float16)v.y;
    dst[2]=(_Float16)v.z; dst[3]=(_Float16)v.w;
  }
  __syncthreads();

  const int cl = w*16 + (l & 15);
  const int c  = u0*4 + cl;           // packed col in [0,512)
  const int ul = cl >> 2;
  const int g  = cl & 3;
  const int cg = g*128 + u0 + ul;     // original column
  const int hi = l >> 4;

  f32x4 acc[4] = {{0,0,0,0},{0,0,0,0},{0,0,0,0},{0,0,0,0}};

  #pragma unroll
  for (int kt = 0; kt < 8; ++kt){
    // B fragment: one 16-B load from the packed table
    const f16x8 bfrag = *(const f16x8*)&Wp[((size_t)((dirc*8 + kt)*512 + c)*4 + hi)*8];
    const int kb = kt*32 + hi*8;
    #pragma unroll
    for (int m = 0; m < 4; ++m){
      const int row = m*16 + (l & 15);
      const int ks  = kb ^ ((row & 7) << 3);
      f16x8 afrag = *(const f16x8*)&As[row*EMBED + ks];
      acc[m] = __builtin_amdgcn_mfma_f32_16x16x32_f16(afrag, bfrag, acc[m], 0, 0, 0);
    }
  }

  const float bv  = (dirc ? bb : bf)[cg];
  const float gsc = (g == 2) ? S_G : S_IFO;
  const float bsc = bv * gsc;
  const int   co  = dirc*512 + c;     // f16 col in EW2
  #pragma unroll
  for (int m = 0; m < 4; ++m){
    #pragma unroll
    for (int r = 0; r < 4; ++r){
      const int vrow = r0 + m*16 + (l >> 4)*4 + r;
      if (vrow < VOCAB)
        EW[(size_t)vrow*GWH + co] = (_Float16)(acc[m][r] + bsc);
    }
  }
}

// ---------------------------------------------------------------------------
// Kernel 2: recurrence, BPB=4 (grid 128, 1 block/CU) — quadruple-confirmed
// 250 us. Step = 620cyc per-CU matrix-pipe issue (invariant for this GEMM)
// + ~500cyc serial h-exchange chain (barrier-required). Per-active-CU
// MFMA 45% + VALU 42% = 87% combined utilization.
// ---------------------------------------------------------------------------
__global__ __launch_bounds__(512, 2) void lstm_b4(
    const int*      __restrict__ tokens,
    const _Float16* __restrict__ EW,
    const float*    __restrict__ Ufw, const float* __restrict__ Ubw,
    float* __restrict__ out)
{
  __shared__ _Float16 h_lds[2][BPB*HSTR];  // 2 x 1.25 KB
  __shared__ int      tok_lds[BPB*TT];     // 8 KB

  const int tid = threadIdx.x;
  const int l   = tid & 63;
  const int w   = tid >> 6;               // wave 0..7
  const int lr  = l & 15;
  const int hi  = l >> 4;
  const int dir = blockIdx.x & 1;
  const int b0  = (blockIdx.x >> 1) * BPB;

  for (int i = tid; i < 2*BPB*HSTR; i += 512) ((_Float16*)h_lds)[i] = (_Float16)0.f;
  for (int i = tid; i < BPB*TT; i += 512)
    tok_lds[i] = tokens[(b0 + (i >> 9))*TT + (i & 511)];
  __syncthreads();

  // ---- resident U B-fragments (pre-scaled): ub[kt][gate], 64 VGPRs ----
  const float* U = dir ? Ubw : Ufw;
  f16x8 ub[4][4];
  #pragma unroll
  for (int kt = 0; kt < 4; ++kt){
    #pragma unroll
    for (int g = 0; g < 4; ++g){
      const int   col = g*128 + w*16 + lr;
      const float gs  = (g == 2) ? S_G : S_IFO;
      f16x8 f;
      #pragma unroll
      for (int j = 0; j < 8; ++j)
        f[j] = (_Float16)(U[(size_t)(kt*32 + hi*8 + j)*G4 + col] * gs);
      ub[kt][g] = f;
    }
  }

  const int bsel = lr >> 2;            // A-row 4j -> batch j (others dup)
  const int q    = hi;                 // gate batch for this lane
  const int u    = w*16 + lr;          // gate hidden unit

  float creg = 0.f, hfin = 0.f;
  const _Float16* ebase = EW + dir*512 + u*4;

  // persistent accumulators: regs 1-3 accumulate garbage, never read
  f32x4 aP[4];
  #pragma unroll
  for (int g = 0; g < 4; ++g) aP[g] = (f32x4){0.f,0.f,0.f,0.f};

  #define AADDR(S) ({ int ss_ = (S); ss_ = ss_ < TT ? ss_ : TT-1;            \
                      const int tt_ = dir ? (TT-1-ss_) : ss_;                \
                      ebase + (size_t)tok_lds[q*TT + tt_]*GWH; })

  f16x4 xwA = *(const f16x4*)AADDR(0);
  f16x4 xwB = *(const f16x4*)AADDR(1);
  const _Float16* adA = AADDR(2);
  const _Float16* adB = AADDR(3);

  #define STEP(XW, AD, SCUR, CUR)                                            \
  {                                                                          \
    const int t_ = dir ? (TT-1-(SCUR)) : (SCUR);                             \
    f16x8 ha[4];                                                             \
    _Pragma("unroll")                                                        \
    for (int kt = 0; kt < 4; ++kt)                                           \
      ha[kt] = *(const f16x8*)&h_lds[CUR][bsel*HSTR + kt*32 + hi*8];         \
    _Pragma("unroll")                                                        \
    for (int g = 0; g < 4; ++g) aP[g][0] = (float)XW[g];                     \
    XW = *(const f16x4*)AD;            /* reload this slot for SCUR+2 */     \
    AD = AADDR((SCUR)+4);              /* address for the next reload */     \
    _Pragma("unroll")                                                        \
    for (int kt = 0; kt < 4; ++kt){                                          \
      _Pragma("unroll")                                                      \
      for (int g = 0; g < 4; ++g)                                            \
        aP[g] = __builtin_amdgcn_mfma_f32_16x16x32_f16(ha[kt], ub[kt][g], aP[g], 0,0,0); \
    }                                                                        \
    {                                                                        \
      const float si = sigm_p(aP[0][0]);                                     \
      const float sf = sigm_p(aP[1][0]);                                     \
      const float tg = tanh_p(aP[2][0]);                                     \
      const float so = sigm_p(aP[3][0]);                                     \
      const float cn = sf*creg + si*tg;                                      \
      creg = cn;                                                             \
      const float hh = so*tanh_rt(cn);                                       \
      hfin = hh;                                                             \
      h_lds[(CUR)^1][q*HSTR + u] = (_Float16)hh;                             \
      out[((size_t)(b0+q)*TT + t_)*(2*HID) + (size_t)dir*HID + u] = hh;      \
    }                                                                        \
    asm volatile("s_waitcnt lgkmcnt(0)" ::: "memory");                       \
    __builtin_amdgcn_s_barrier();                                            \
  }

  for (int s = 0; s < TT; s += 2){
    STEP(xwA, adA, s,     0)
    STEP(xwB, adB, s + 1, 1)
  }
  #undef STEP
  #undef AADDR

  // ---- final h_T / c_T (each thread owns one (batch,unit)) ----
  {
    const size_t O1  = (size_t)BB*TT*(2*HID);
    const size_t idx = (size_t)(b0+q)*HID + u;
    if (dir == 0){
      out[O1                    + idx] = hfin;
      out[O1 +   (size_t)BB*HID + idx] = creg;
    } else {
      out[O1 + 2*(size_t)BB*HID + idx] = hfin;
      out[O1 + 3*(size_t)BB*HID + idx] = creg;
    }
  }
}

extern "C" void kernel_launch(void* const* d_in, const int* in_sizes, int n_in,
                              void* d_out, int out_size, void* d_ws, size_t ws_size,
                              hipStream_t stream)
{
  const int*   tokens = (const int*)  d_in[0];
  const float* emb    = (const float*)d_in[1];
  const float* Wf     = (const float*)d_in[2];
  const float* Ufw    = (const float*)d_in[3];
  const float* bf     = (const float*)d_in[4];
  const float* Wb     = (const float*)d_in[5];
  const float* Ubw    = (const float*)d_in[6];
  const float* bb     = (const float*)d_in[7];
  float* out = (float*)d_out;
  _Float16* EW = (_Float16*)d_ws;                       // 61.44 MB
  _Float16* Wp = (_Float16*)d_ws + (size_t)VOCAB*GWH;   // +1 MB packed W

  wpack<<<128, 256, 0, stream>>>(Wf, Wb, Wp);
  embw_mfma<<<dim3((VOCAB + 63)/64, 16), 256, 0, stream>>>(emb, Wp, bf, bb, EW);
  lstm_b4<<<(BB/BPB)*2, 512, 0, stream>>>(tokens, EW, Ufw, Ubw, out);
}

// Round 20
// 296.796 us; speedup vs baseline: 1.2339x; 1.0838x over previous
//
#include <hip/hip_runtime.h>
#include <hip/hip_bf16.h>
#include <stdint.h>

#define VOCAB 30000
#define EMBED 256
#define HID   128
#define BB    256
#define TT    512
#define G4    512        // gate columns per direction
#define GWH   1024       // f16 columns in EW2 ([dir][u][g] packed)
#define BPB   4          // batches per lstm block (D-rows 0,4,8,12)
#define HSTR  160        // f16 stride per batch row in h_lds (320 B)

typedef _Float16 f16x8 __attribute__((ext_vector_type(8)));
typedef _Float16 f16x4 __attribute__((ext_vector_type(4)));
typedef float    f32x4 __attribute__((ext_vector_type(4)));

// gate scales folded into EW / Wp / U at build time:
//   i,f,o : z' = -log2(e)  * z   -> sigm = rcp(1 + exp2(z'))
//   g     : z' = +2log2(e) * z   -> tanh = 1 - 2*rcp(1 + exp2(z'))
#define S_IFO (-1.4426950408889634f)
#define S_G   ( 2.8853900817779268f)

__device__ __forceinline__ float fexp2(float x){
#if __has_builtin(__builtin_amdgcn_exp2f)
  return __builtin_amdgcn_exp2f(x);
#else
  return exp2f(x);
#endif
}
__device__ __forceinline__ float frcp(float x){
#if __has_builtin(__builtin_amdgcn_rcpf)
  return __builtin_amdgcn_rcpf(x);
#else
  return 1.0f/x;
#endif
}
__device__ __forceinline__ float sigm_p(float zp){ return frcp(1.0f + fexp2(zp)); }
__device__ __forceinline__ float tanh_p(float zp){ return 1.0f - 2.0f*frcp(1.0f + fexp2(zp)); }
__device__ __forceinline__ float tanh_rt(float x){ return 1.0f - 2.0f*frcp(1.0f + fexp2(S_G*x)); }

// ---------------------------------------------------------------------------
// Kernel 0a: pre-convert emb to f16 row-major (ONE f32->f16 pass instead of
// 16 per element inside embw). 46 MB traffic ~ 7 us.
// ---------------------------------------------------------------------------
__global__ __launch_bounds__(256) void epack(
    const float* __restrict__ emb, _Float16* __restrict__ Ep)
{
  const size_t idx = (size_t)blockIdx.x*256 + threadIdx.x;  // 960000 chunks of 8
  const float4* s = (const float4*)(emb + idx*8);
  const float4 a = s[0], b = s[1];
  f16x8 v = { (_Float16)a.x, (_Float16)a.y, (_Float16)a.z, (_Float16)a.w,
              (_Float16)b.x, (_Float16)b.y, (_Float16)b.z, (_Float16)b.w };
  *(f16x8*)&Ep[idx*8] = v;
}

// ---------------------------------------------------------------------------
// Kernel 0b: pack W into B-fragment layout, f16, pre-scaled.
// Wp[dirc][kt][c][hi][j] ; c = u*4+g (packed col), k = kt*32 + hi*8 + j.
// ---------------------------------------------------------------------------
__global__ __launch_bounds__(256) void wpack(
    const float* __restrict__ Wf, const float* __restrict__ Wb,
    _Float16* __restrict__ Wp)
{
  const int idx  = blockIdx.x*256 + threadIdx.x;   // 32768 = 2*8*512*4
  const int hi   = idx & 3;
  const int c    = (idx >> 2) & 511;
  const int kt   = (idx >> 11) & 7;
  const int dirc = idx >> 14;
  const float* W = dirc ? Wb : Wf;
  const int g = c & 3, u = c >> 2;
  const int cg = g*128 + u;                        // original column
  const float gs = (g == 2) ? S_G : S_IFO;
  f16x8 v;
  #pragma unroll
  for (int j = 0; j < 8; ++j)
    v[j] = (_Float16)(W[(size_t)(kt*32 + hi*8 + j)*G4 + cg] * gs);
  *(f16x8*)&Wp[(size_t)idx*8] = v;
}

// ---------------------------------------------------------------------------
// Kernel 1: EW2[v][dirc*512 + c] = f16( emb[v]@W(c)*gsc + b*gsc )
// Grid (469, 16) — measured optimum. A staged from the f16 Ep table:
// restage L3 traffic halves (491 -> 245 MB), staging = 16B load +
// ds_write_b128 per 8 elems (no per-element cvt). Same As layout
// bit-identically (XOR swizzle is 8-elem-granular).
// ---------------------------------------------------------------------------
__global__ __launch_bounds__(256, 4) void embw_mfma(
    const _Float16* __restrict__ Ep,
    const _Float16* __restrict__ Wp,
    const float* __restrict__ bf, const float* __restrict__ bb,
    _Float16* __restrict__ EW)
{
  __shared__ _Float16 As[64*EMBED];   // 32 KB
  const int tid  = threadIdx.x;
  const int l    = tid & 63;
  const int w    = tid >> 6;
  const int r0   = blockIdx.x * 64;
  const int dirc = blockIdx.y >> 3;
  const int u0   = (blockIdx.y & 7) * 16;
  const int nr   = min(64, VOCAB - r0);

  const f16x8* asrc = (const f16x8*)(Ep + (size_t)r0*EMBED);
  for (int i = tid; i < nr*(EMBED/8); i += 256){
    f16x8 v = asrc[i];
    const int row = i >> 5;            // 32 chunks of 8 per row
    const int kc  = (i & 31) * 8;
    const int ks  = kc ^ ((row & 7) << 3);
    *(f16x8*)&As[row*EMBED + ks] = v;
  }
  __syncthreads();

  const int cl = w*16 + (l & 15);
  const int c  = u0*4 + cl;           // packed col in [0,512)
  const int ul = cl >> 2;
  const int g  = cl & 3;
  const int cg = g*128 + u0 + ul;     // original column
  const int hi = l >> 4;

  f32x4 acc[4] = {{0,0,0,0},{0,0,0,0},{0,0,0,0},{0,0,0,0}};

  #pragma unroll
  for (int kt = 0; kt < 8; ++kt){
    // B fragment: one 16-B load from the packed table
    const f16x8 bfrag = *(const f16x8*)&Wp[((size_t)((dirc*8 + kt)*512 + c)*4 + hi)*8];
    const int kb = kt*32 + hi*8;
    #pragma unroll
    for (int m = 0; m < 4; ++m){
      const int row = m*16 + (l & 15);
      const int ks  = kb ^ ((row & 7) << 3);
      f16x8 afrag = *(const f16x8*)&As[row*EMBED + ks];
      acc[m] = __builtin_amdgcn_mfma_f32_16x16x32_f16(afrag, bfrag, acc[m], 0, 0, 0);
    }
  }

  const float bv  = (dirc ? bb : bf)[cg];
  const float gsc = (g == 2) ? S_G : S_IFO;
  const float bsc = bv * gsc;
  const int   co  = dirc*512 + c;     // f16 col in EW2
  #pragma unroll
  for (int m = 0; m < 4; ++m){
    #pragma unroll
    for (int r = 0; r < 4; ++r){
      const int vrow = r0 + m*16 + (l >> 4)*4 + r;
      if (vrow < VOCAB)
        EW[(size_t)vrow*GWH + co] = (_Float16)(acc[m][r] + bsc);
    }
  }
}

// ---------------------------------------------------------------------------
// Kernel 2: recurrence, BPB=4 (grid 128, 1 block/CU) — quintuple-confirmed
// 250 us. Step = 620cyc per-CU matrix-pipe issue (invariant for this GEMM)
// + ~500cyc serial h-exchange chain (barrier-required). Per-active-CU
// MFMA 45% + VALU 42% = 87% combined utilization.
// ---------------------------------------------------------------------------
__global__ __launch_bounds__(512, 2) void lstm_b4(
    const int*      __restrict__ tokens,
    const _Float16* __restrict__ EW,
    const float*    __restrict__ Ufw, const float* __restrict__ Ubw,
    float* __restrict__ out)
{
  __shared__ _Float16 h_lds[2][BPB*HSTR];  // 2 x 1.25 KB
  __shared__ int      tok_lds[BPB*TT];     // 8 KB

  const int tid = threadIdx.x;
  const int l   = tid & 63;
  const int w   = tid >> 6;               // wave 0..7
  const int lr  = l & 15;
  const int hi  = l >> 4;
  const int dir = blockIdx.x & 1;
  const int b0  = (blockIdx.x >> 1) * BPB;

  for (int i = tid; i < 2*BPB*HSTR; i += 512) ((_Float16*)h_lds)[i] = (_Float16)0.f;
  for (int i = tid; i < BPB*TT; i += 512)
    tok_lds[i] = tokens[(b0 + (i >> 9))*TT + (i & 511)];
  __syncthreads();

  // ---- resident U B-fragments (pre-scaled): ub[kt][gate], 64 VGPRs ----
  const float* U = dir ? Ubw : Ufw;
  f16x8 ub[4][4];
  #pragma unroll
  for (int kt = 0; kt < 4; ++kt){
    #pragma unroll
    for (int g = 0; g < 4; ++g){
      const int   col = g*128 + w*16 + lr;
      const float gs  = (g == 2) ? S_G : S_IFO;
      f16x8 f;
      #pragma unroll
      for (int j = 0; j < 8; ++j)
        f[j] = (_Float16)(U[(size_t)(kt*32 + hi*8 + j)*G4 + col] * gs);
      ub[kt][g] = f;
    }
  }

  const int bsel = lr >> 2;            // A-row 4j -> batch j (others dup)
  const int q    = hi;                 // gate batch for this lane
  const int u    = w*16 + lr;          // gate hidden unit

  float creg = 0.f, hfin = 0.f;
  const _Float16* ebase = EW + dir*512 + u*4;

  // persistent accumulators: regs 1-3 accumulate garbage, never read
  f32x4 aP[4];
  #pragma unroll
  for (int g = 0; g < 4; ++g) aP[g] = (f32x4){0.f,0.f,0.f,0.f};

  #define AADDR(S) ({ int ss_ = (S); ss_ = ss_ < TT ? ss_ : TT-1;            \
                      const int tt_ = dir ? (TT-1-ss_) : ss_;                \
                      ebase + (size_t)tok_lds[q*TT + tt_]*GWH; })

  f16x4 xwA = *(const f16x4*)AADDR(0);
  f16x4 xwB = *(const f16x4*)AADDR(1);
  const _Float16* adA = AADDR(2);
  const _Float16* adB = AADDR(3);

  #define STEP(XW, AD, SCUR, CUR)                                            \
  {                                                                          \
    const int t_ = dir ? (TT-1-(SCUR)) : (SCUR);                             \
    f16x8 ha[4];                                                             \
    _Pragma("unroll")                                                        \
    for (int kt = 0; kt < 4; ++kt)                                           \
      ha[kt] = *(const f16x8*)&h_lds[CUR][bsel*HSTR + kt*32 + hi*8];         \
    _Pragma("unroll")                                                        \
    for (int g = 0; g < 4; ++g) aP[g][0] = (float)XW[g];                     \
    XW = *(const f16x4*)AD;            /* reload this slot for SCUR+2 */     \
    AD = AADDR((SCUR)+4);              /* address for the next reload */     \
    _Pragma("unroll")                                                        \
    for (int kt = 0; kt < 4; ++kt){                                          \
      _Pragma("unroll")                                                      \
      for (int g = 0; g < 4; ++g)                                            \
        aP[g] = __builtin_amdgcn_mfma_f32_16x16x32_f16(ha[kt], ub[kt][g], aP[g], 0,0,0); \
    }                                                                        \
    {                                                                        \
      const float si = sigm_p(aP[0][0]);                                     \
      const float sf = sigm_p(aP[1][0]);                                     \
      const float tg = tanh_p(aP[2][0]);                                     \
      const float so = sigm_p(aP[3][0]);                                     \
      const float cn = sf*creg + si*tg;                                      \
      creg = cn;                                                             \
      const float hh = so*tanh_rt(cn);                                       \
      hfin = hh;                                                             \
      h_lds[(CUR)^1][q*HSTR + u] = (_Float16)hh;                             \
      out[((size_t)(b0+q)*TT + t_)*(2*HID) + (size_t)dir*HID + u] = hh;      \
    }                                                                        \
    asm volatile("s_waitcnt lgkmcnt(0)" ::: "memory");                       \
    __builtin_amdgcn_s_barrier();                                            \
  }

  for (int s = 0; s < TT; s += 2){
    STEP(xwA, adA, s,     0)
    STEP(xwB, adB, s + 1, 1)
  }
  #undef STEP
  #undef AADDR

  // ---- final h_T / c_T (each thread owns one (batch,unit)) ----
  {
    const size_t O1  = (size_t)BB*TT*(2*HID);
    const size_t idx = (size_t)(b0+q)*HID + u;
    if (dir == 0){
      out[O1                    + idx] = hfin;
      out[O1 +   (size_t)BB*HID + idx] = creg;
    } else {
      out[O1 + 2*(size_t)BB*HID + idx] = hfin;
      out[O1 + 3*(size_t)BB*HID + idx] = creg;
    }
  }
}

extern "C" void kernel_launch(void* const* d_in, const int* in_sizes, int n_in,
                              void* d_out, int out_size, void* d_ws, size_t ws_size,
                              hipStream_t stream)
{
  const int*   tokens = (const int*)  d_in[0];
  const float* emb    = (const float*)d_in[1];
  const float* Wf     = (const float*)d_in[2];
  const float* Ufw    = (const float*)d_in[3];
  const float* bf     = (const float*)d_in[4];
  const float* Wb     = (const float*)d_in[5];
  const float* Ubw    = (const float*)d_in[6];
  const float* bb     = (const float*)d_in[7];
  float* out = (float*)d_out;
  _Float16* EW = (_Float16*)d_ws;                            // 61.44 MB
  _Float16* Wp = (_Float16*)d_ws + (size_t)VOCAB*GWH;        // +1 MB packed W
  _Float16* Ep = Wp + (size_t)2*8*512*4*8;                   // +15.36 MB f16 emb

  epack<<<(VOCAB*EMBED/8 + 255)/256, 256, 0, stream>>>(emb, Ep);
  wpack<<<128, 256, 0, stream>>>(Wf, Wb, Wp);
  embw_mfma<<<dim3((VOCAB + 63)/64, 16), 256, 0, stream>>>(Ep, Wp, bf, bb, EW);
  lstm_b4<<<(BB/BPB)*2, 512, 0, stream>>>(tokens, EW, Ufw, Ubw, out);
}